// Round 9
// baseline (153.429 us; speedup 1.0000x reference)
//
#include <hip/hip_runtime.h>
#include <hip/hip_fp16.h>

// ---------------- types ----------------
typedef __attribute__((ext_vector_type(8))) short short8;
typedef __attribute__((ext_vector_type(4))) float f32x4;

#define GLOBAL_AS __attribute__((address_space(1)))
#define LDS_AS __attribute__((address_space(3)))

static __device__ __forceinline__ void gload16(const void* g, void* l) {
    __builtin_amdgcn_global_load_lds((const GLOBAL_AS void*)g, (LDS_AS void*)l, 16, 0, 0);
}

#define SBAR() __builtin_amdgcn_s_barrier()
#define WAITVM(N) asm volatile("s_waitcnt vmcnt(" #N ")" ::: "memory")
#define WAITLGKM0() do { asm volatile("s_waitcnt lgkmcnt(0)" ::: "memory"); \
                         __builtin_amdgcn_sched_barrier(0); } while (0)

// float -> bf16 RNE via bit trick
static __device__ __forceinline__ unsigned short f2bf(float f) {
    union { float f; unsigned u; } v; v.f = f;
    unsigned r = v.u + 0x7FFFu + ((v.u >> 16) & 1u);
    return (unsigned short)(r >> 16);
}

// ---------------- kernel 1: fused prep (unchanged from round 8) ----------------
__global__ __launch_bounds__(256) void prep_kernel(
    const int* __restrict__ packed,      // [4096][2048] one byte value per int
    const float* __restrict__ scales,    // [4096]
    const void* __restrict__ vals,       // [nnz] dtype auto-detected
    const int* __restrict__ idxs,        // [nnz]
    const int* __restrict__ ptr,         // [4097]
    uint4* __restrict__ Wb4,             // [4096][512] uint4 = 8 bf16
    const float* __restrict__ x,
    unsigned short* __restrict__ xb)
{
    if (blockIdx.x >= 4096) {
        const int n8 = (4096 * 4096) / 8;
        const int stride = 2048 * 256;
        for (int j = (blockIdx.x - 4096) * 256 + threadIdx.x; j < n8; j += stride) {
            const float4 a = ((const float4*)x)[2 * (size_t)j];
            const float4 b = ((const float4*)x)[2 * (size_t)j + 1];
            short8 o;
            o[0] = (short)f2bf(a.x); o[1] = (short)f2bf(a.y);
            o[2] = (short)f2bf(a.z); o[3] = (short)f2bf(a.w);
            o[4] = (short)f2bf(b.x); o[5] = (short)f2bf(b.y);
            o[6] = (short)f2bf(b.z); o[7] = (short)f2bf(b.w);
            *(short8*)(xb + 8 * (size_t)j) = o;
        }
        return;
    }
    __shared__ float sp[4096];
    __shared__ int sc[3];
    const int row = blockIdx.x;
    float4* sp4 = (float4*)sp;
    const float4 z4 = make_float4(0.f, 0.f, 0.f, 0.f);
    for (int i = threadIdx.x; i < 1024; i += 256) sp4[i] = z4;
    {
        const int wvp = threadIdx.x >> 6, ln = threadIdx.x & 63;
        if (wvp < 3) {
            int c = 0;
            for (int i = ln; i < 192; i += 64) {
                float a;
                if (wvp == 0) a = fabsf(((const float*)vals)[i]);
                else if (wvp == 1) a = fabsf(__half2float(((const __half*)vals)[i]));
                else { union { unsigned u; float fv; } cc;
                       cc.u = ((unsigned)((const unsigned short*)vals)[i]) << 16;
                       a = fabsf(cc.fv); }
                c += (a >= 1e-5f && a <= 0.5f) ? 1 : 0;
            }
            for (int o = 32; o; o >>= 1) c += __shfl_down(c, o);
            if (ln == 0) sc[wvp] = c;
        }
    }
    __syncthreads();
    const int kind = (sc[0] >= sc[1] && sc[0] >= sc[2]) ? 0 : (sc[1] >= sc[2] ? 1 : 2);
    const int s = ptr[row], e = ptr[row + 1];
    if (kind == 0) {
        const float* vf = (const float*)vals;
        for (int i = s + threadIdx.x; i < e; i += 256) atomicAdd(&sp[idxs[i]], vf[i]);
    } else if (kind == 1) {
        const __half* vh = (const __half*)vals;
        for (int i = s + threadIdx.x; i < e; i += 256) atomicAdd(&sp[idxs[i]], __half2float(vh[i]));
    } else {
        const unsigned short* vb = (const unsigned short*)vals;
        for (int i = s + threadIdx.x; i < e; i += 256) {
            union { unsigned u; float fv; } c; c.u = ((unsigned)vb[i]) << 16;
            atomicAdd(&sp[idxs[i]], c.fv);
        }
    }
    __syncthreads();
    const float sc_ = scales[row];
    const int4* prow4 = (const int4*)(packed + (size_t)row * 2048);
    uint4* wrow4 = Wb4 + (size_t)row * 512;
    for (int j = threadIdx.x; j < 512; j += 256) {
        const int4 p = prow4[j];
        const float* spc = sp + 8 * j;
        uint4 o;
        o.x = (unsigned)f2bf((float)((p.x & 0xF) - 8) * sc_ + spc[0]) |
              ((unsigned)f2bf((float)(((p.x >> 4) & 0xF) - 8) * sc_ + spc[1]) << 16);
        o.y = (unsigned)f2bf((float)((p.y & 0xF) - 8) * sc_ + spc[2]) |
              ((unsigned)f2bf((float)(((p.y >> 4) & 0xF) - 8) * sc_ + spc[3]) << 16);
        o.z = (unsigned)f2bf((float)((p.z & 0xF) - 8) * sc_ + spc[4]) |
              ((unsigned)f2bf((float)(((p.z >> 4) & 0xF) - 8) * sc_ + spc[5]) << 16);
        o.w = (unsigned)f2bf((float)((p.w & 0xF) - 8) * sc_ + spc[6]) |
              ((unsigned)f2bf((float)(((p.w >> 4) & 0xF) - 8) * sc_ + spc[7]) << 16);
        wrow4[j] = o;
    }
}

// ---------------- kernel 2: m201-style 8-phase paced 256x256 GEMM ----------------
// C[M,N]=A[M,K]*B[N,K]^T, 16x16x32 bf16, 8 waves (2Mx4N), BK=64, 2x64KB dbuf.
// Per K-tile: 4 phases, each {ds_reads; 2 gload_lds stage; SBAR; lgkmcnt(0);
// setprio(1); 16 MFMA; setprio(0); [gate]; SBAR}. Gates = counted vmcnt(6) at
// end of P0 (A1(t) ready) and end of P3 (A0,Blo,Bhi(t+1) ready) -- derived:
// at each gate the 6 youngest outstanding loads are exactly the not-yet-needed
// ones. Every waited load is >=4 phases (~2000cyc) old.
// Halves are wave-interleaved so phase->half is compile-time: A-half h =
// rows {h*64..h*64+63, 128+h*64..+63}; read base h=mh, round r=wr. B likewise
// with h=wc&1, r=wc>>1; both B halves gate at P0 (B is read P0(kk0)+P2(kk1);
// kk-split staging would be the round-7 64B-row conflict trap).
// Stage schedule: P0: Bhi(t+1); P1: A1(t+1); P3: A0(t+2)+Blo(t+2). Targets
// freed >=1 full barrier before the stage issues (ledger in analysis).
// Swizzle identical to r5/r8 (measured 0 conflicts).
__global__ __launch_bounds__(512, 2) void gemm_bt_kernel(
    const unsigned short* __restrict__ A,   // bf16 bits, M x K
    const unsigned short* __restrict__ B,   // bf16 bits, N x K
    float* __restrict__ C)                  // fp32, M x N
{
    constexpr int K = 4096;
    constexpr int N = 4096;
    constexpr int NT = K / 64;   // 64 K-tiles
    __shared__ __attribute__((aligned(128))) char smem[131072]; // 2 x {A0,A1,Blo,Bhi} x 16KB

    const int tid = threadIdx.x;
    const int lane = tid & 63;
    const int wv = tid >> 6;              // 0..7
    const int bid = (blockIdx.x & 7) * 32 + (blockIdx.x >> 3);  // bijective XCD swizzle
    const int bm = bid >> 4;              // 16 M-tiles
    const int bn = bid & 15;              // 16 N-tiles

    // ---- staging: one gload16 round (512 thr x 16B = 8KB) = 64 rows x 128B ----
    const int grow = tid >> 3;                          // 0..63 row within round
    const int sg = (tid & 7) ^ (grow & 7);              // pre-swizzled 16B segment
    const unsigned short* ag = A + (size_t)(bm * 256 + grow) * K + sg * 8;
    const unsigned short* bg = B + (size_t)(bn * 256 + grow) * K + sg * 8;

    // half H, round R covers operand rows H*64 + R*128 + (0..63)
#define STA(H, R, KT, BUF)                                                             \
    gload16(ag + (size_t)((H) * 64 + (R) * 128) * K + (KT),                            \
            smem + (BUF) * 65536 + (H) * 16384 + (R) * 8192 + wv * 1024);
#define STB(H, R, KT, BUF)                                                             \
    gload16(bg + (size_t)((H) * 64 + (R) * 128) * K + (KT),                            \
            smem + (BUF) * 65536 + 32768 + (H) * 16384 + (R) * 8192 + wv * 1024);

    // ---- fragment read geometry ----
    const int wr = wv >> 2, wc = wv & 3;                // 2x4 wave grid
    const int khw = lane >> 4;                          // 0..3
    const int rx = lane & 7;                            // == rowInRound&7
    const int arow = (lane & 15) * 128 + wr * 8192;     // A: + MH*16384 + m*2048
    const int brow = 32768 + (wc & 1) * 16384 + (wc >> 1) * 8192 + (lane & 15) * 128;

#define LDA4(DST, MH, KK, BUF)                                                         \
    {                                                                                  \
        _Pragma("unroll") for (int m = 0; m < 4; ++m)                                  \
            DST[m] = *(const short8*)(smem + (BUF) * 65536 + (MH) * 16384 + arow +     \
                                      m * 2048 + (((((KK) << 2) + khw) ^ rx) << 4));   \
    }
#define LDB4(DST, KK, BUF)                                                             \
    {                                                                                  \
        _Pragma("unroll") for (int n = 0; n < 4; ++n)                                  \
            DST[n] = *(const short8*)(smem + (BUF) * 65536 + brow + n * 2048 +         \
                                      (((((KK) << 2) + khw) ^ rx) << 4));              \
    }
#define MFMA16(AF, BF, MH)                                                             \
    {                                                                                  \
        __builtin_amdgcn_s_setprio(1);                                                 \
        _Pragma("unroll") for (int m = 0; m < 4; ++m)                                  \
            _Pragma("unroll") for (int n = 0; n < 4; ++n)                              \
                acc[(MH) * 4 + m][n] = __builtin_amdgcn_mfma_f32_16x16x32_bf16(        \
                    AF[m], BF[n], acc[(MH) * 4 + m][n], 0, 0, 0);                      \
        __builtin_amdgcn_s_setprio(0);                                                 \
    }

    f32x4 acc[8][4];
#pragma unroll
    for (int m = 0; m < 8; ++m)
#pragma unroll
        for (int n = 0; n < 4; ++n) acc[m][n] = (f32x4)0.0f;

    // ---- prologue: A0(0),Blo(0),Bhi(0),A1(0),A0(1),Blo(1) = 12 loads ----
    STA(0, 0, 0, 0); STA(0, 1, 0, 0);
    STB(0, 0, 0, 0); STB(0, 1, 0, 0);
    STB(1, 0, 0, 0); STB(1, 1, 0, 0);
    STA(1, 0, 0, 0); STA(1, 1, 0, 0);
    STA(0, 0, 64, 1); STA(0, 1, 64, 1);
    STB(0, 0, 64, 1); STB(0, 1, 64, 1);
    WAITVM(6);   // A0(0),Blo(0),Bhi(0) landed; 6 younger in flight
    SBAR();

    for (int t = 0; t < NT; ++t) {
        const int cur = t & 1, nxt = cur ^ 1;
        const int ktn = (t + 1) * 64, ktn2 = (t + 2) * 64;
        const bool s1 = (t + 1 < NT), s2 = (t + 2 < NT);
        __builtin_amdgcn_sched_barrier(0);

        short8 af0[4], af1[4], bf0[4], bf1[4];
        // ---- P0: (mh0,kk0); stage Bhi(t+1) ----
        LDA4(af0, 0, 0, cur); LDB4(bf0, 0, cur);
        if (s1) { STB(1, 0, ktn, nxt); STB(1, 1, ktn, nxt); }
        SBAR();
        WAITLGKM0();
        MFMA16(af0, bf0, 0);
        if (s1) { WAITVM(6); } else { WAITVM(0); }   // G1: A1(t) ready
        SBAR();
        // ---- P1: (mh1,kk0); stage A1(t+1) ----
        LDA4(af1, 1, 0, cur);
        if (s1) { STA(1, 0, ktn, nxt); STA(1, 1, ktn, nxt); }
        SBAR();
        WAITLGKM0();
        MFMA16(af1, bf0, 1);
        SBAR();
        // ---- P2: (mh0,kk1); no stage ----
        LDA4(af0, 0, 1, cur); LDB4(bf1, 1, cur);
        SBAR();
        WAITLGKM0();
        MFMA16(af0, bf1, 0);
        SBAR();
        // ---- P3: (mh1,kk1); stage A0(t+2)+Blo(t+2) ----
        LDA4(af1, 1, 1, cur);
        if (s2) { STA(0, 0, ktn2, cur); STA(0, 1, ktn2, cur);
                  STB(0, 0, ktn2, cur); STB(0, 1, ktn2, cur); }
        SBAR();
        WAITLGKM0();
        MFMA16(af1, bf1, 1);
        if (s2) { WAITVM(6); } else { WAITVM(0); }   // G0: A0,Blo,Bhi(t+1) ready
        SBAR();
    }

    // ---- epilogue: C/D layout col=lane&15, row=(lane>>4)*4+reg ----
    const int crow0 = bm * 256 + wr * 128 + (lane >> 4) * 4;
    const int ccol0 = bn * 256 + wc * 64 + (lane & 15);
#pragma unroll
    for (int m = 0; m < 8; ++m)
#pragma unroll
        for (int n = 0; n < 4; ++n)
#pragma unroll
            for (int r = 0; r < 4; ++r)
                C[(size_t)(crow0 + m * 16 + r) * N + ccol0 + n * 16] = acc[m][n][r];
}

// ---------------- launch ----------------
extern "C" void kernel_launch(void* const* d_in, const int* in_sizes, int n_in,
                              void* d_out, int out_size, void* d_ws, size_t ws_size,
                              hipStream_t stream) {
    const float* x        = (const float*)d_in[0];
    const int* packed     = (const int*)d_in[1];
    const float* scales   = (const float*)d_in[2];
    const void* vals      = (const void*)d_in[3];
    const int* idxs       = (const int*)d_in[4];
    const int* ptr        = (const int*)d_in[5];
    float* out            = (float*)d_out;

    unsigned short* Wb = (unsigned short*)d_ws;            // 4096*4096 bf16 = 32 MB
    unsigned short* Xb = Wb + (size_t)4096 * 4096;         // next 32 MB

    prep_kernel<<<6144, 256, 0, stream>>>(packed, scales, vals, idxs, ptr,
                                          (uint4*)Wb, x, Xb);
    gemm_bt_kernel<<<256, 512, 0, stream>>>(Xb, Wb, out);
}